// Round 1
// baseline (812.831 us; speedup 1.0000x reference)
//
#include <hip/hip_runtime.h>
#include <stdint.h>

typedef __bf16 bf16;
typedef bf16 bf16x8 __attribute__((ext_vector_type(8)));
typedef float f32x4 __attribute__((ext_vector_type(4)));

#define N_NODES 131072
#define D_IN    128
#define KEXP    1024
#define H_DIM   512
#define NGRP    4
#define NPG     32768   // N_NODES / NGRP
#define F_SEG   8192
#define G_SEG   32
#define C_OUT   16

// ---------------------------------------------------------------------------
// One-time weight transpose + fp32->bf16 cast.
// W1T[g][k][d] = W1[g][d][k]   (so GEMM1 B-frags read contiguous along d=K)
// W2T[g][n][k] = W2[g][k][n]   (so GEMM2 B-frags read contiguous along k=K)
// ---------------------------------------------------------------------------
__global__ void convert_weights(const float* __restrict__ W1,
                                const float* __restrict__ W2,
                                bf16* __restrict__ W1T,
                                bf16* __restrict__ W2T)
{
    int i = blockIdx.x * 256 + threadIdx.x;
    const int n1 = NGRP * KEXP * D_IN;   // 524288
    const int n2 = NGRP * H_DIM * KEXP;  // 2097152
    if (i < n1) {
        int d = i & (D_IN - 1);
        int k = (i >> 7) & (KEXP - 1);
        int g = i >> 17;
        W1T[i] = (bf16)W1[((size_t)(g * D_IN + d)) * KEXP + k];
    } else {
        int j = i - n1;
        if (j < n2) {
            int k = j & (KEXP - 1);
            int n = (j >> 10) & (H_DIM - 1);
            int g = j >> 19;
            W2T[j] = (bf16)W2[((size_t)(g * KEXP + k)) * H_DIM + n];
        }
    }
}

// ---------------------------------------------------------------------------
// Fused gather + GEMM1(relu) + GEMM2 + scatter.
// Block: 256 threads (4 waves). Tile: 128 nodes x 128 of H, K-chunks of 64.
// h chunk lives only in LDS (recomputed per BN tile; factor H/BN = 4 on GEMM1).
// LDS: sX 32K + sW1 16K + sH 16K + sW2 16K = 80 KB -> 2 blocks/CU.
// MFMA 16x16x32_bf16 layouts (learn_hip-verified):
//   A[m=lane&15][k=(lane>>4)*8+j], B[k=(lane>>4)*8+j][n=lane&15],
//   D[row=(lane>>4)*4+r][col=lane&15]
// ---------------------------------------------------------------------------
__global__ __launch_bounds__(256, 2)
void mlp_kernel(const float* __restrict__ x,
                const int*   __restrict__ gidx,
                const bf16*  __restrict__ W1T,
                const float* __restrict__ b1,
                const bf16*  __restrict__ W2T,
                const float* __restrict__ b2,
                bf16*        __restrict__ NF)
{
    __shared__ bf16 sX[128 * 128];   // x tile     [m][d]
    __shared__ bf16 sW1[64 * 128];   // W1T chunk  [k'][d]   (n-major for B-frag)
    __shared__ bf16 sH[128 * 64];    // h chunk    [m][k']
    __shared__ bf16 sW2[128 * 64];   // W2T chunk  [n'][k']

    const int tid   = threadIdx.x;
    const int bid   = blockIdx.x;
    const int g     = bid >> 10;
    const int rem   = bid & 1023;
    const int m0    = (rem >> 2) * 128;
    const int n0    = (rem & 3) * 128;

    const int wave = tid >> 6;
    const int lane = tid & 63;
    const int ln   = lane & 15;
    const int quad = lane >> 4;
    const int w32  = wave * 32;

    const int*   gI  = gidx + g * NPG + m0;
    const bf16*  W1g = W1T + (size_t)g * KEXP * D_IN;
    const bf16*  W2g = W2T + (size_t)g * H_DIM * KEXP;
    const float* b1g = b1 + g * KEXP;
    const float* b2g = b2 + g * H_DIM;

    // ---- gather x tile, fp32 -> bf16 ----
    {
        int r  = tid >> 5;    // 0..7
        int c4 = tid & 31;    // float4 column
        #pragma unroll
        for (int it = 0; it < 16; ++it) {
            int m = it * 8 + r;
            int node = gI[m];
            float4 v = ((const float4*)(x + (size_t)node * D_IN))[c4];
            int o = m * 128 + c4 * 4;
            sX[o + 0] = (bf16)v.x;
            sX[o + 1] = (bf16)v.y;
            sX[o + 2] = (bf16)v.z;
            sX[o + 3] = (bf16)v.w;
        }
    }

    f32x4 acc2[2][8];
    #pragma unroll
    for (int a = 0; a < 2; ++a)
        #pragma unroll
        for (int b = 0; b < 8; ++b)
            acc2[a][b] = (f32x4){0.f, 0.f, 0.f, 0.f};

    #pragma unroll 1
    for (int kc = 0; kc < 16; ++kc) {
        const int kc0 = kc * 64;
        __syncthreads();   // previous chunk's LDS reads complete

        // stage W1T chunk [64][128]
        {
            int row = tid >> 4;  // 0..15 per pass
            int c   = tid & 15;
            #pragma unroll
            for (int it = 0; it < 4; ++it) {
                int rr = it * 16 + row;
                *(uint4*)(sW1 + rr * 128 + c * 8) =
                    *(const uint4*)(W1g + (size_t)(kc0 + rr) * 128 + c * 8);
            }
        }
        // stage W2T chunk [128][64]
        {
            int row = tid >> 3;  // 0..31 per pass
            int c   = tid & 7;
            #pragma unroll
            for (int it = 0; it < 4; ++it) {
                int rr = it * 32 + row;
                *(uint4*)(sW2 + rr * 64 + c * 8) =
                    *(const uint4*)(W2g + (size_t)(n0 + rr) * 1024 + kc0 + c * 8);
            }
        }
        __syncthreads();   // staging visible

        // ---- stage 1: hc[32 rows of this wave][64] = relu(x @ W1c + b1) ----
        f32x4 acc1[2][4];
        #pragma unroll
        for (int a = 0; a < 2; ++a)
            #pragma unroll
            for (int b = 0; b < 4; ++b)
                acc1[a][b] = (f32x4){0.f, 0.f, 0.f, 0.f};

        #pragma unroll
        for (int ks = 0; ks < 4; ++ks) {
            int kk = ks * 32;
            bf16x8 af[2];
            #pragma unroll
            for (int mt = 0; mt < 2; ++mt)
                af[mt] = *(const bf16x8*)(sX + (w32 + mt * 16 + ln) * 128 + kk + quad * 8);
            #pragma unroll
            for (int nt = 0; nt < 4; ++nt) {
                bf16x8 bfr = *(const bf16x8*)(sW1 + (nt * 16 + ln) * 128 + kk + quad * 8);
                #pragma unroll
                for (int mt = 0; mt < 2; ++mt)
                    acc1[mt][nt] = __builtin_amdgcn_mfma_f32_16x16x32_bf16(
                        af[mt], bfr, acc1[mt][nt], 0, 0, 0);
            }
        }
        // bias + relu -> sH (rows w32..w32+31 are wave-private: no barrier)
        #pragma unroll
        for (int nt = 0; nt < 4; ++nt) {
            int ncol = nt * 16 + ln;
            float bias = b1g[kc0 + ncol];
            #pragma unroll
            for (int mt = 0; mt < 2; ++mt)
                #pragma unroll
                for (int r = 0; r < 4; ++r) {
                    int mrow = w32 + mt * 16 + quad * 4 + r;
                    float v = acc1[mt][nt][r] + bias;
                    sH[mrow * 64 + ncol] = (bf16)fmaxf(v, 0.f);
                }
        }

        // ---- stage 2: og += hc @ W2c ----
        #pragma unroll
        for (int ks = 0; ks < 2; ++ks) {
            int kk = ks * 32;
            bf16x8 a2[2];
            #pragma unroll
            for (int mt = 0; mt < 2; ++mt)
                a2[mt] = *(const bf16x8*)(sH + (w32 + mt * 16 + ln) * 64 + kk + quad * 8);
            #pragma unroll
            for (int nt = 0; nt < 8; ++nt) {
                bf16x8 b2f = *(const bf16x8*)(sW2 + (nt * 16 + ln) * 64 + kk + quad * 8);
                #pragma unroll
                for (int mt = 0; mt < 2; ++mt)
                    acc2[mt][nt] = __builtin_amdgcn_mfma_f32_16x16x32_bf16(
                        a2[mt], b2f, acc2[mt][nt], 0, 0, 0);
            }
        }
    }

    // ---- epilogue: + b2, scatter rows to NF[node][H] as bf16 ----
    #pragma unroll
    for (int mt = 0; mt < 2; ++mt)
        #pragma unroll
        for (int r = 0; r < 4; ++r) {
            int mrow = w32 + mt * 16 + quad * 4 + r;
            int node = gI[mrow];
            bf16* dst = NF + (size_t)node * H_DIM + n0;
            #pragma unroll
            for (int nt = 0; nt < 8; ++nt) {
                int col = nt * 16 + ln;
                dst[col] = (bf16)(acc2[mt][nt][r] + b2g[n0 + col]);
            }
        }
}

// ---------------------------------------------------------------------------
// segment_max over 16 consecutive nodes per fine cluster (sorted arange ids).
// Thread handles one (f, channel-pair). 2 bf16 per uint load.
// ---------------------------------------------------------------------------
__global__ void pool_kernel(const bf16* __restrict__ NF, float* __restrict__ EMB)
{
    int t  = blockIdx.x * 256 + threadIdx.x;    // 8192*256 total
    int f  = t >> 8;
    int hp = (t & 255) * 2;
    const uint32_t* src = (const uint32_t*)NF;
    size_t base = (size_t)f * 4096 + (hp >> 1); // uint index of row f*16, col hp
    float lo = -INFINITY, hi = -INFINITY;
    #pragma unroll
    for (int r = 0; r < 16; ++r) {
        uint32_t v = src[base + (size_t)r * 256];
        lo = fmaxf(lo, __uint_as_float(v << 16));
        hi = fmaxf(hi, __uint_as_float(v & 0xffff0000u));
    }
    *(float2*)(EMB + (size_t)f * 512 + hp) = make_float2(lo, hi);
}

// ---------------------------------------------------------------------------
// Per (coarse group, channel) mean / rsqrt(var+eps) over 256 fine rows.
// ---------------------------------------------------------------------------
__global__ void stats_kernel(const float* __restrict__ EMB,
                             float* __restrict__ MEAN,
                             float* __restrict__ RSIG)
{
    int gc = blockIdx.x;
    int ch = blockIdx.y * 128 + threadIdx.x;
    const float* p = EMB + (size_t)gc * 256 * 512 + ch;
    float s = 0.f, ss = 0.f;
    #pragma unroll 4
    for (int r = 0; r < 256; ++r) {
        float v = p[(size_t)r * 512];
        s += v; ss += v * v;
    }
    float mean = s * (1.f / 256.f);
    float var  = ss * (1.f / 256.f) - mean * mean;
    MEAN[gc * 512 + ch] = mean;
    RSIG[gc * 512 + ch] = rsqrtf(var + 1e-5f);
}

// ---------------------------------------------------------------------------
// logits[f][c] = b_out[c] + sum_h (emb[f][h]-mean)*rsig * w_out[h][c]
// Block: 16 f-rows x 16 classes; w_out and normalized emb tile staged in LDS.
// ---------------------------------------------------------------------------
__global__ __launch_bounds__(256)
void classifier_kernel(const float* __restrict__ EMB,
                       const float* __restrict__ MEAN,
                       const float* __restrict__ RSIG,
                       const float* __restrict__ w_out,
                       const float* __restrict__ b_out,
                       float* __restrict__ out)
{
    __shared__ float sW[512 * 16];
    __shared__ float sE[16 * 513];   // +1 pad breaks 4-way bank conflict
    int t  = threadIdx.x;
    int f0 = blockIdx.x * 16;
    int gc = f0 >> 8;

    #pragma unroll
    for (int it = 0; it < 8; ++it) {
        int i = (it * 256 + t) * 4;
        *(float4*)(sW + i) = *(const float4*)(w_out + i);
    }
    #pragma unroll
    for (int it = 0; it < 32; ++it) {
        int i  = it * 256 + t;
        int fr = i >> 9;
        int h  = i & 511;
        float v = EMB[(size_t)(f0 + fr) * 512 + h];
        sE[fr * 513 + h] = (v - MEAN[gc * 512 + h]) * RSIG[gc * 512 + h];
    }
    __syncthreads();

    int fr = t >> 4;
    int c  = t & 15;
    float acc = b_out[c];
    #pragma unroll 8
    for (int h = 0; h < 512; ++h)
        acc += sE[fr * 513 + h] * sW[h * 16 + c];
    out[(size_t)(f0 + fr) * 16 + c] = acc;
}

// ---------------------------------------------------------------------------
// Workspace layout (~156.4 MB):
//   W1T 1 MB | W2T 4 MB | NF 134 MB | EMB 16 MB | MEAN 64K | RSIG 64K
// ---------------------------------------------------------------------------
extern "C" void kernel_launch(void* const* d_in, const int* in_sizes, int n_in,
                              void* d_out, int out_size, void* d_ws, size_t ws_size,
                              hipStream_t stream)
{
    const float* x     = (const float*)d_in[0];
    const int*   gidx  = (const int*)d_in[1];
    const float* W1    = (const float*)d_in[4];
    const float* b1    = (const float*)d_in[5];
    const float* W2    = (const float*)d_in[6];
    const float* b2    = (const float*)d_in[7];
    const float* w_out = (const float*)d_in[8];
    const float* b_out = (const float*)d_in[9];
    float* out = (float*)d_out;

    char* w = (char*)d_ws;
    bf16* W1T = (bf16*)w;  w += (size_t)NGRP * KEXP * D_IN * 2;
    bf16* W2T = (bf16*)w;  w += (size_t)NGRP * H_DIM * KEXP * 2;
    bf16* NF  = (bf16*)w;  w += (size_t)N_NODES * H_DIM * 2;
    float* EMB  = (float*)w; w += (size_t)F_SEG * H_DIM * 4;
    float* MEAN = (float*)w; w += (size_t)G_SEG * H_DIM * 4;
    float* RSIG = (float*)w; w += (size_t)G_SEG * H_DIM * 4;

    convert_weights<<<10240, 256, 0, stream>>>(W1, W2, W1T, W2T);
    mlp_kernel<<<4096, 256, 0, stream>>>(x, gidx, W1T, b1, W2T, b2, NF);
    pool_kernel<<<8192, 256, 0, stream>>>(NF, EMB);
    stats_kernel<<<dim3(32, 4), 128, 0, stream>>>(EMB, MEAN, RSIG);
    classifier_kernel<<<512, 256, 0, stream>>>(EMB, MEAN, RSIG, w_out, b_out, out);
}

// Round 2
// 512.521 us; speedup vs baseline: 1.5859x; 1.5859x over previous
//
#include <hip/hip_runtime.h>
#include <stdint.h>

typedef __bf16 bf16;
typedef bf16 bf16x8 __attribute__((ext_vector_type(8)));
typedef float f32x4 __attribute__((ext_vector_type(4)));

#define N_NODES 131072
#define D_IN    128
#define KEXP    1024
#define H_DIM   512
#define NGRP    4
#define NPG     32768   // N_NODES / NGRP
#define F_SEG   8192
#define G_SEG   32
#define C_OUT   16

// ---------------------------------------------------------------------------
// One-time weight cast + swizzle into MFMA-fragment order (16x16x32 bf16).
// B-frag layout: lane (quad=lane>>4, ln=lane&15) holds B[k=quad*8+j][n=ln].
//
// W1F[g][kc(16)][f=ks*4+nt (16)][slot=lane (64)][j (8)]
//     = W1[g][d = ks*32 + quad*8 + j][k' = kc*64 + nt*16 + ln]
// W2F[g][n0t(4)][kc(16)][f=ks2*8+nt (16)][slot][j]
//     = W2[g][k = kc*64 + ks2*32 + quad*8 + j][n = n0t*128 + nt*16 + ln]
// ---------------------------------------------------------------------------
__global__ void convert_weights(const float* __restrict__ W1,
                                const float* __restrict__ W2,
                                bf16* __restrict__ W1F,
                                bf16* __restrict__ W2F)
{
    int t = blockIdx.x * 256 + threadIdx.x;
    if (t < 65536) {
        int slot = t & 63, f = (t >> 6) & 15, kc = (t >> 10) & 15, g = t >> 14;
        int ks = f >> 2, nt = f & 3, quad = slot >> 4, ln = slot & 15;
        int k = kc * 64 + nt * 16 + ln;
        const float* src = W1 + ((size_t)(g * 128 + ks * 32 + quad * 8)) * 1024 + k;
        bf16x8 v;
        #pragma unroll
        for (int j = 0; j < 8; ++j) v[j] = (bf16)src[(size_t)j * 1024];
        *(bf16x8*)(W1F + (size_t)t * 8) = v;
    } else {
        int u = t - 65536;
        if (u < 262144) {
            int slot = u & 63, f = (u >> 6) & 15, kc = (u >> 10) & 15;
            int n0t = (u >> 14) & 3, g = u >> 16;
            int ks2 = f >> 3, nt = f & 7, quad = slot >> 4, ln = slot & 15;
            int k = kc * 64 + ks2 * 32 + quad * 8;
            int n = n0t * 128 + nt * 16 + ln;
            const float* src = W2 + ((size_t)(g * 1024 + k)) * 512 + n;
            bf16x8 v;
            #pragma unroll
            for (int j = 0; j < 8; ++j) v[j] = (bf16)src[(size_t)j * 512];
            *(bf16x8*)(W2F + (size_t)u * 8) = v;
        }
    }
}

// ---------------------------------------------------------------------------
// Fused gather + GEMM1(relu) + GEMM2 + scatter. 256 threads (4 waves).
// Tile: 128 nodes x 128 of H; K-chunks of 64 over KEXP; h lives in LDS only.
// ALL LDS buffers in fragment order [frag][lane][8] -> every MFMA frag load
// is ds_read_b128 at base+lane*16: conflict-free. (Round-1 row-major layout
// was a 16-way conflict on every frag read: 2.56e8 conflict cycles.)
// LDS: sX 32K + sW1 16K + sH 16K + sW2 16K = 80 KB -> 2 blocks/CU.
// sX and sH are wave-private (rows wave*32..+31) -> no extra barriers.
// ---------------------------------------------------------------------------
__global__ __launch_bounds__(256, 2)
void mlp_kernel(const float* __restrict__ x,
                const int*   __restrict__ gidx,
                const bf16*  __restrict__ W1F,
                const float* __restrict__ b1,
                const bf16*  __restrict__ W2F,
                const float* __restrict__ b2,
                bf16*        __restrict__ NF)
{
    // fragment-order tiles: [frag][lane(64)][8 bf16]
    __shared__ __align__(16) bf16 sX[16384];  // [wave(4)][mt(2)*4+ks(4)][lane][8]
    __shared__ __align__(16) bf16 sW1[8192];  // [ks(4)*4+nt(4)][lane][8]
    __shared__ __align__(16) bf16 sH[8192];   // [wave(4)][mt(2)*2+ks2(2)][lane][8]
    __shared__ __align__(16) bf16 sW2[8192];  // [ks2(2)*8+nt(8)][lane][8]

    const int tid  = threadIdx.x;
    const int bid  = blockIdx.x;
    const int g    = bid >> 10;
    const int rem  = bid & 1023;
    const int m0   = (rem >> 2) * 128;
    const int n0t  = rem & 3;

    const int wave = tid >> 6;
    const int lane = tid & 63;
    const int quad = lane >> 4;
    const int ln   = lane & 15;

    const int*  gI  = gidx + g * NPG + m0;
    const bf16* W1g = W1F + (size_t)g * 131072;                  // [kc][8192]
    const bf16* W2g = W2F + (size_t)(g * 4 + n0t) * 131072;      // [kc][8192]
    const float* b1g = b1 + g * KEXP;
    const float* b2g = b2 + g * H_DIM + n0t * 128;

    // ---- gather x -> sX in fragment order (wave-private frags) ----
    // frag f = wave*8 + mt*4 + ks; lane (quad,ln) holds
    // x[row = wave*32+mt*16+ln][d = ks*32+quad*8 .. +8)
    #pragma unroll
    for (int i = 0; i < 8; ++i) {
        int f   = wave * 8 + i;                  // mt = i>>2, ks = i&3
        int row = wave * 32 + (i >> 2) * 16 + ln;
        int node = gI[row];
        const float* src = x + (size_t)node * D_IN + (i & 3) * 32 + quad * 8;
        float4 a = *(const float4*)src;
        float4 b = *(const float4*)(src + 4);
        bf16x8 v;
        v[0] = (bf16)a.x; v[1] = (bf16)a.y; v[2] = (bf16)a.z; v[3] = (bf16)a.w;
        v[4] = (bf16)b.x; v[5] = (bf16)b.y; v[6] = (bf16)b.z; v[7] = (bf16)b.w;
        *(bf16x8*)(sX + (f * 64 + lane) * 8) = v;
    }

    f32x4 acc2[2][8];
    #pragma unroll
    for (int a = 0; a < 2; ++a)
        #pragma unroll
        for (int b = 0; b < 8; ++b)
            acc2[a][b] = (f32x4){0.f, 0.f, 0.f, 0.f};

    #pragma unroll 1
    for (int kc = 0; kc < 16; ++kc) {
        __syncthreads();   // gather/previous-iter LDS reads complete
        // ---- stage weight frags: straight 16B copies, conflict-free ----
        {
            const bf16* w1src = W1g + (size_t)kc * 8192;
            const bf16* w2src = W2g + (size_t)kc * 8192;
            #pragma unroll
            for (int r = 0; r < 4; ++r) {
                int o = (r * 256 + tid) * 8;
                *(uint4*)(sW1 + o) = *(const uint4*)(w1src + o);
                *(uint4*)(sW2 + o) = *(const uint4*)(w2src + o);
            }
        }
        __syncthreads();

        // ---- stage 1: h[wave rows 32][k' 64] = relu(x @ W1c + b1) ----
        f32x4 acc1[2][4];
        #pragma unroll
        for (int a = 0; a < 2; ++a)
            #pragma unroll
            for (int b = 0; b < 4; ++b)
                acc1[a][b] = (f32x4){0.f, 0.f, 0.f, 0.f};

        #pragma unroll
        for (int ks = 0; ks < 4; ++ks) {
            bf16x8 af[2];
            #pragma unroll
            for (int mt = 0; mt < 2; ++mt)
                af[mt] = *(const bf16x8*)(sX + ((wave * 8 + mt * 4 + ks) * 64 + lane) * 8);
            #pragma unroll
            for (int nt = 0; nt < 4; ++nt) {
                bf16x8 bfr = *(const bf16x8*)(sW1 + ((ks * 4 + nt) * 64 + lane) * 8);
                #pragma unroll
                for (int mt = 0; mt < 2; ++mt)
                    acc1[mt][nt] = __builtin_amdgcn_mfma_f32_16x16x32_bf16(
                        af[mt], bfr, acc1[mt][nt], 0, 0, 0);
            }
        }

        // bias+relu -> sH in fragment order (wave-private; no barrier needed)
        // value (m = w32+mt*16+quad*4+reg, k' = nt*16+ln) goes to
        // frag (mt, ks2=nt>>1), slot = ((nt&1)*2 + ln>>3)*16 + quad*4+reg, j = ln&7
        #pragma unroll
        for (int nt = 0; nt < 4; ++nt) {
            float bias = b1g[kc * 64 + nt * 16 + ln];
            int base = wave * 2048 + ((nt & 1) * 2 + (ln >> 3)) * 128
                     + quad * 32 + (ln & 7);
            #pragma unroll
            for (int mt = 0; mt < 2; ++mt) {
                int fb = base + (mt * 2 + (nt >> 1)) * 512;
                #pragma unroll
                for (int reg = 0; reg < 4; ++reg) {
                    float v = acc1[mt][nt][reg] + bias;
                    sH[fb + reg * 8] = (bf16)fmaxf(v, 0.f);
                }
            }
        }

        // ---- stage 2: og += h @ W2c ----
        #pragma unroll
        for (int ks2 = 0; ks2 < 2; ++ks2) {
            bf16x8 a2[2];
            #pragma unroll
            for (int mt = 0; mt < 2; ++mt)
                a2[mt] = *(const bf16x8*)(sH + (wave * 2048) + ((mt * 2 + ks2) * 64 + lane) * 8);
            #pragma unroll
            for (int nt = 0; nt < 8; ++nt) {
                bf16x8 bb = *(const bf16x8*)(sW2 + ((ks2 * 8 + nt) * 64 + lane) * 8);
                #pragma unroll
                for (int mt = 0; mt < 2; ++mt)
                    acc2[mt][nt] = __builtin_amdgcn_mfma_f32_16x16x32_bf16(
                        a2[mt], bb, acc2[mt][nt], 0, 0, 0);
            }
        }
    }

    // ---- epilogue: + b2, scatter rows to NF[node][H] as bf16 ----
    #pragma unroll
    for (int mt = 0; mt < 2; ++mt)
        #pragma unroll
        for (int reg = 0; reg < 4; ++reg) {
            int row  = wave * 32 + mt * 16 + quad * 4 + reg;
            int node = gI[row];
            bf16* dst = NF + (size_t)node * H_DIM + n0t * 128;
            #pragma unroll
            for (int nt = 0; nt < 8; ++nt) {
                int col = nt * 16 + ln;
                dst[col] = (bf16)(acc2[mt][nt][reg] + b2g[col]);
            }
        }
}

// ---------------------------------------------------------------------------
// segment_max over 16 consecutive nodes per fine cluster (sorted arange ids).
// ---------------------------------------------------------------------------
__global__ void pool_kernel(const bf16* __restrict__ NF, float* __restrict__ EMB)
{
    int t  = blockIdx.x * 256 + threadIdx.x;    // 8192*256 total
    int f  = t >> 8;
    int hp = (t & 255) * 2;
    const uint32_t* src = (const uint32_t*)NF;
    size_t base = (size_t)f * 4096 + (hp >> 1);
    float lo = -INFINITY, hi = -INFINITY;
    #pragma unroll
    for (int r = 0; r < 16; ++r) {
        uint32_t v = src[base + (size_t)r * 256];
        lo = fmaxf(lo, __uint_as_float(v << 16));
        hi = fmaxf(hi, __uint_as_float(v & 0xffff0000u));
    }
    *(float2*)(EMB + (size_t)f * 512 + hp) = make_float2(lo, hi);
}

// ---------------------------------------------------------------------------
// Per (coarse group, channel) mean / rsqrt(var+eps) over 256 fine rows.
// ---------------------------------------------------------------------------
__global__ void stats_kernel(const float* __restrict__ EMB,
                             float* __restrict__ MEAN,
                             float* __restrict__ RSIG)
{
    int gc = blockIdx.x;
    int ch = blockIdx.y * 128 + threadIdx.x;
    const float* p = EMB + (size_t)gc * 256 * 512 + ch;
    float s = 0.f, ss = 0.f;
    #pragma unroll 4
    for (int r = 0; r < 256; ++r) {
        float v = p[(size_t)r * 512];
        s += v; ss += v * v;
    }
    float mean = s * (1.f / 256.f);
    float var  = ss * (1.f / 256.f) - mean * mean;
    MEAN[gc * 512 + ch] = mean;
    RSIG[gc * 512 + ch] = rsqrtf(var + 1e-5f);
}

// ---------------------------------------------------------------------------
// logits[f][c] = b_out[c] + sum_h (emb[f][h]-mean)*rsig * w_out[h][c]
// ---------------------------------------------------------------------------
__global__ __launch_bounds__(256)
void classifier_kernel(const float* __restrict__ EMB,
                       const float* __restrict__ MEAN,
                       const float* __restrict__ RSIG,
                       const float* __restrict__ w_out,
                       const float* __restrict__ b_out,
                       float* __restrict__ out)
{
    __shared__ float sW[512 * 16];
    __shared__ float sE[16 * 513];   // +1 pad breaks 4-way bank conflict
    int t  = threadIdx.x;
    int f0 = blockIdx.x * 16;
    int gc = f0 >> 8;

    #pragma unroll
    for (int it = 0; it < 8; ++it) {
        int i = (it * 256 + t) * 4;
        *(float4*)(sW + i) = *(const float4*)(w_out + i);
    }
    #pragma unroll
    for (int it = 0; it < 32; ++it) {
        int i  = it * 256 + t;
        int fr = i >> 9;
        int h  = i & 511;
        float v = EMB[(size_t)(f0 + fr) * 512 + h];
        sE[fr * 513 + h] = (v - MEAN[gc * 512 + h]) * RSIG[gc * 512 + h];
    }
    __syncthreads();

    int fr = t >> 4;
    int c  = t & 15;
    float acc = b_out[c];
    #pragma unroll 8
    for (int h = 0; h < 512; ++h)
        acc += sE[fr * 513 + h] * sW[h * 16 + c];
    out[(size_t)(f0 + fr) * 16 + c] = acc;
}

// ---------------------------------------------------------------------------
// Workspace layout (~156.4 MB):
//   W1F 1 MB | W2F 4 MB | NF 134 MB | EMB 16 MB | MEAN 64K | RSIG 64K
// ---------------------------------------------------------------------------
extern "C" void kernel_launch(void* const* d_in, const int* in_sizes, int n_in,
                              void* d_out, int out_size, void* d_ws, size_t ws_size,
                              hipStream_t stream)
{
    const float* x     = (const float*)d_in[0];
    const int*   gidx  = (const int*)d_in[1];
    const float* W1    = (const float*)d_in[4];
    const float* b1    = (const float*)d_in[5];
    const float* W2    = (const float*)d_in[6];
    const float* b2    = (const float*)d_in[7];
    const float* w_out = (const float*)d_in[8];
    const float* b_out = (const float*)d_in[9];
    float* out = (float*)d_out;

    char* w = (char*)d_ws;
    bf16* W1F = (bf16*)w;  w += (size_t)NGRP * KEXP * D_IN * 2;
    bf16* W2F = (bf16*)w;  w += (size_t)NGRP * H_DIM * KEXP * 2;
    bf16* NF  = (bf16*)w;  w += (size_t)N_NODES * H_DIM * 2;
    float* EMB  = (float*)w; w += (size_t)F_SEG * H_DIM * 4;
    float* MEAN = (float*)w; w += (size_t)G_SEG * H_DIM * 4;
    float* RSIG = (float*)w; w += (size_t)G_SEG * H_DIM * 4;

    convert_weights<<<1280, 256, 0, stream>>>(W1, W2, W1F, W2F);
    mlp_kernel<<<4096, 256, 0, stream>>>(x, gidx, W1F, b1, W2F, b2, NF);
    pool_kernel<<<8192, 256, 0, stream>>>(NF, EMB);
    stats_kernel<<<dim3(32, 4), 128, 0, stream>>>(EMB, MEAN, RSIG);
    classifier_kernel<<<512, 256, 0, stream>>>(EMB, MEAN, RSIG, w_out, b_out, out);
}

// Round 3
// 437.322 us; speedup vs baseline: 1.8587x; 1.1720x over previous
//
#include <hip/hip_runtime.h>
#include <stdint.h>

typedef __bf16 bf16;
typedef bf16 bf16x8 __attribute__((ext_vector_type(8)));
typedef float f32x4 __attribute__((ext_vector_type(4)));

#define N_NODES 131072
#define D_IN    128
#define KEXP    1024
#define H_DIM   512
#define NGRP    4
#define NPG     32768   // N_NODES / NGRP
#define F_SEG   8192
#define G_SEG   32
#define C_OUT   16

// async global->LDS DMA, 16B per lane; LDS dest = wave-uniform base + lane*16
typedef const __attribute__((address_space(1))) void* gas_t;
typedef __attribute__((address_space(3))) void* las_t;
__device__ __forceinline__ void cp16_async(const bf16* g, bf16* l) {
    __builtin_amdgcn_global_load_lds((gas_t)g, (las_t)l, 16, 0, 0);
}

// ---------------------------------------------------------------------------
// One-time weight cast + swizzle into MFMA-fragment order (16x16x32 bf16).
// B-frag layout: lane (quad=lane>>4, ln=lane&15) holds B[k=quad*8+j][n=ln].
//
// W1F[g][kc(16)][f=ks*4+nt (16)][slot=lane (64)][j (8)]
//     = W1[g][d = ks*32 + quad*8 + j][k' = kc*64 + nt*16 + ln]
// W2F[g][n0t(4)][kc(16)][f=ks2*8+nt (16)][slot][j]
//     = W2[g][k = kc*64 + ks2*32 + quad*8 + j][n = n0t*128 + nt*16 + ln]
// ---------------------------------------------------------------------------
__global__ void convert_weights(const float* __restrict__ W1,
                                const float* __restrict__ W2,
                                bf16* __restrict__ W1F,
                                bf16* __restrict__ W2F)
{
    int t = blockIdx.x * 256 + threadIdx.x;
    if (t < 65536) {
        int slot = t & 63, f = (t >> 6) & 15, kc = (t >> 10) & 15, g = t >> 14;
        int ks = f >> 2, nt = f & 3, quad = slot >> 4, ln = slot & 15;
        int k = kc * 64 + nt * 16 + ln;
        const float* src = W1 + ((size_t)(g * 128 + ks * 32 + quad * 8)) * 1024 + k;
        bf16x8 v;
        #pragma unroll
        for (int j = 0; j < 8; ++j) v[j] = (bf16)src[(size_t)j * 1024];
        *(bf16x8*)(W1F + (size_t)t * 8) = v;
    } else {
        int u = t - 65536;
        if (u < 262144) {
            int slot = u & 63, f = (u >> 6) & 15, kc = (u >> 10) & 15;
            int n0t = (u >> 14) & 3, g = u >> 16;
            int ks2 = f >> 3, nt = f & 7, quad = slot >> 4, ln = slot & 15;
            int k = kc * 64 + ks2 * 32 + quad * 8;
            int n = n0t * 128 + nt * 16 + ln;
            const float* src = W2 + ((size_t)(g * 1024 + k)) * 512 + n;
            bf16x8 v;
            #pragma unroll
            for (int j = 0; j < 8; ++j) v[j] = (bf16)src[(size_t)j * 512];
            *(bf16x8*)(W2F + (size_t)u * 8) = v;
        }
    }
}

// ---------------------------------------------------------------------------
// Fused gather + GEMM1(relu) + GEMM2 + scatter. 256 threads (4 waves).
// Tile: 128 nodes x 128 of H; K-chunks of 64 over KEXP; h lives in LDS only.
// Round-3 changes vs round-2:
//  - x A-frags loaded ONCE into 32 VGPRs (wave-private, reused all 16 kc) —
//    sX (32 KB) deleted.
//  - W1/W2 chunks staged via global_load_lds dwordx4 (async DMA, no VGPR
//    round-trip); fragment-order layout == wave-uniform base + lane*16.
//  - LDS 80 -> 48 KB: 3 blocks/CU (12 waves/CU) so cross-block overlap
//    hides the barrier-bounded staging drain (m97 mechanism).
// ---------------------------------------------------------------------------
__global__ __launch_bounds__(256, 3)
void mlp_kernel(const float* __restrict__ x,
                const int*   __restrict__ gidx,
                const bf16*  __restrict__ W1F,
                const float* __restrict__ b1,
                const bf16*  __restrict__ W2F,
                const float* __restrict__ b2,
                bf16*        __restrict__ NF)
{
    // fragment-order tiles: [frag(16)][lane(64)][8 bf16]
    __shared__ __align__(16) bf16 sW1[8192];  // [ks(4)*4+nt(4)][lane][8]
    __shared__ __align__(16) bf16 sH[8192];   // [wave(4)][mt(2)*2+ks2(2)][lane][8]
    __shared__ __align__(16) bf16 sW2[8192];  // [ks2(2)*8+nt(8)][lane][8]

    const int tid  = threadIdx.x;
    const int bid  = blockIdx.x;
    const int g    = bid >> 10;
    const int rem  = bid & 1023;
    const int m0   = (rem >> 2) * 128;
    const int n0t  = rem & 3;

    const int wave = tid >> 6;
    const int lane = tid & 63;
    const int quad = lane >> 4;
    const int ln   = lane & 15;

    const int*  gI  = gidx + g * NPG + m0;
    const bf16* W1g = W1F + (size_t)g * 131072;                  // [kc][8192]
    const bf16* W2g = W2F + (size_t)(g * 4 + n0t) * 131072;      // [kc][8192]
    const float* b1g = b1 + g * KEXP;
    const float* b2g = b2 + g * H_DIM + n0t * 128;

    // ---- gather x A-frags straight into registers (reused all 16 kc) ----
    // frag i (mt=i>>2, ks=i&3): lane holds x[row=wave*32+mt*16+ln][ks*32+quad*8 ..+8)
    bf16x8 xf[8];
    #pragma unroll
    for (int i = 0; i < 8; ++i) {
        int row  = wave * 32 + (i >> 2) * 16 + ln;
        int node = gI[row];
        const float* src = x + (size_t)node * D_IN + (i & 3) * 32 + quad * 8;
        float4 a = *(const float4*)src;
        float4 b = *(const float4*)(src + 4);
        bf16x8 v;
        v[0] = (bf16)a.x; v[1] = (bf16)a.y; v[2] = (bf16)a.z; v[3] = (bf16)a.w;
        v[4] = (bf16)b.x; v[5] = (bf16)b.y; v[6] = (bf16)b.z; v[7] = (bf16)b.w;
        xf[i] = v;
    }

    f32x4 acc2[2][8];
    #pragma unroll
    for (int a = 0; a < 2; ++a)
        #pragma unroll
        for (int b = 0; b < 8; ++b)
            acc2[a][b] = (f32x4){0.f, 0.f, 0.f, 0.f};

    #pragma unroll 1
    for (int kc = 0; kc < 16; ++kc) {
        __syncthreads();   // previous iter's LDS reads complete before overwrite

        // ---- async-DMA weight frags: 1 KB per instruction, 4+4 per wave ----
        {
            const bf16* w1src = W1g + (size_t)kc * 8192;
            const bf16* w2src = W2g + (size_t)kc * 8192;
            #pragma unroll
            for (int r = 0; r < 4; ++r) {
                int c = r * 4 + wave;          // chunk = one frag (64 lanes x 16B)
                cp16_async(w1src + c * 512 + lane * 8, sW1 + c * 512);
                cp16_async(w2src + c * 512 + lane * 8, sW2 + c * 512);
            }
        }
        __syncthreads();   // vmcnt(0) drain: deposits visible

        // ---- stage 1: h[wave rows 32][k' 64] = relu(x @ W1c + b1) ----
        float bias_v[4];
        #pragma unroll
        for (int nt = 0; nt < 4; ++nt)
            bias_v[nt] = b1g[kc * 64 + nt * 16 + ln];

        f32x4 acc1[2][4];
        #pragma unroll
        for (int a = 0; a < 2; ++a)
            #pragma unroll
            for (int b = 0; b < 4; ++b)
                acc1[a][b] = (f32x4){0.f, 0.f, 0.f, 0.f};

        #pragma unroll
        for (int ks = 0; ks < 4; ++ks) {
            #pragma unroll
            for (int nt = 0; nt < 4; ++nt) {
                bf16x8 bfr = *(const bf16x8*)(sW1 + ((ks * 4 + nt) * 64 + lane) * 8);
                #pragma unroll
                for (int mt = 0; mt < 2; ++mt)
                    acc1[mt][nt] = __builtin_amdgcn_mfma_f32_16x16x32_bf16(
                        xf[mt * 4 + ks], bfr, acc1[mt][nt], 0, 0, 0);
            }
        }

        // bias+relu -> sH in fragment order (wave-private; no barrier needed)
        #pragma unroll
        for (int nt = 0; nt < 4; ++nt) {
            float bias = bias_v[nt];
            int base = wave * 2048 + ((nt & 1) * 2 + (ln >> 3)) * 128
                     + quad * 32 + (ln & 7);
            #pragma unroll
            for (int mt = 0; mt < 2; ++mt) {
                int fb = base + (mt * 2 + (nt >> 1)) * 512;
                #pragma unroll
                for (int reg = 0; reg < 4; ++reg) {
                    float v = acc1[mt][nt][reg] + bias;
                    sH[fb + reg * 8] = (bf16)fmaxf(v, 0.f);
                }
            }
        }

        // ---- stage 2: og += h @ W2c ----
        #pragma unroll
        for (int ks2 = 0; ks2 < 2; ++ks2) {
            bf16x8 a2[2];
            #pragma unroll
            for (int mt = 0; mt < 2; ++mt)
                a2[mt] = *(const bf16x8*)(sH + (wave * 2048) + ((mt * 2 + ks2) * 64 + lane) * 8);
            #pragma unroll
            for (int nt = 0; nt < 8; ++nt) {
                bf16x8 bb = *(const bf16x8*)(sW2 + ((ks2 * 8 + nt) * 64 + lane) * 8);
                #pragma unroll
                for (int mt = 0; mt < 2; ++mt)
                    acc2[mt][nt] = __builtin_amdgcn_mfma_f32_16x16x32_bf16(
                        a2[mt], bb, acc2[mt][nt], 0, 0, 0);
            }
        }
    }

    // ---- epilogue: + b2, scatter rows to NF[node][H] as bf16 ----
    #pragma unroll
    for (int mt = 0; mt < 2; ++mt)
        #pragma unroll
        for (int reg = 0; reg < 4; ++reg) {
            int row  = wave * 32 + mt * 16 + quad * 4 + reg;
            int node = gI[row];
            bf16* dst = NF + (size_t)node * H_DIM + n0t * 128;
            #pragma unroll
            for (int nt = 0; nt < 8; ++nt) {
                int col = nt * 16 + ln;
                dst[col] = (bf16)(acc2[mt][nt][reg] + b2g[col]);
            }
        }
}

// ---------------------------------------------------------------------------
// segment_max over 16 consecutive nodes per fine cluster (sorted arange ids).
// ---------------------------------------------------------------------------
__global__ void pool_kernel(const bf16* __restrict__ NF, float* __restrict__ EMB)
{
    int t  = blockIdx.x * 256 + threadIdx.x;    // 8192*256 total
    int f  = t >> 8;
    int hp = (t & 255) * 2;
    const uint32_t* src = (const uint32_t*)NF;
    size_t base = (size_t)f * 4096 + (hp >> 1);
    float lo = -INFINITY, hi = -INFINITY;
    #pragma unroll
    for (int r = 0; r < 16; ++r) {
        uint32_t v = src[base + (size_t)r * 256];
        lo = fmaxf(lo, __uint_as_float(v << 16));
        hi = fmaxf(hi, __uint_as_float(v & 0xffff0000u));
    }
    *(float2*)(EMB + (size_t)f * 512 + hp) = make_float2(lo, hi);
}

// ---------------------------------------------------------------------------
// Per (coarse group, channel) mean / rsqrt(var+eps) over 256 fine rows.
// ---------------------------------------------------------------------------
__global__ void stats_kernel(const float* __restrict__ EMB,
                             float* __restrict__ MEAN,
                             float* __restrict__ RSIG)
{
    int gc = blockIdx.x;
    int ch = blockIdx.y * 128 + threadIdx.x;
    const float* p = EMB + (size_t)gc * 256 * 512 + ch;
    float s = 0.f, ss = 0.f;
    #pragma unroll 4
    for (int r = 0; r < 256; ++r) {
        float v = p[(size_t)r * 512];
        s += v; ss += v * v;
    }
    float mean = s * (1.f / 256.f);
    float var  = ss * (1.f / 256.f) - mean * mean;
    MEAN[gc * 512 + ch] = mean;
    RSIG[gc * 512 + ch] = rsqrtf(var + 1e-5f);
}

// ---------------------------------------------------------------------------
// logits[f][c] = b_out[c] + sum_h (emb[f][h]-mean)*rsig * w_out[h][c]
// ---------------------------------------------------------------------------
__global__ __launch_bounds__(256)
void classifier_kernel(const float* __restrict__ EMB,
                       const float* __restrict__ MEAN,
                       const float* __restrict__ RSIG,
                       const float* __restrict__ w_out,
                       const float* __restrict__ b_out,
                       float* __restrict__ out)
{
    __shared__ float sW[512 * 16];
    __shared__ float sE[16 * 513];   // +1 pad breaks 4-way bank conflict
    int t  = threadIdx.x;
    int f0 = blockIdx.x * 16;
    int gc = f0 >> 8;

    #pragma unroll
    for (int it = 0; it < 8; ++it) {
        int i = (it * 256 + t) * 4;
        *(float4*)(sW + i) = *(const float4*)(w_out + i);
    }
    #pragma unroll
    for (int it = 0; it < 32; ++it) {
        int i  = it * 256 + t;
        int fr = i >> 9;
        int h  = i & 511;
        float v = EMB[(size_t)(f0 + fr) * 512 + h];
        sE[fr * 513 + h] = (v - MEAN[gc * 512 + h]) * RSIG[gc * 512 + h];
    }
    __syncthreads();

    int fr = t >> 4;
    int c  = t & 15;
    float acc = b_out[c];
    #pragma unroll 8
    for (int h = 0; h < 512; ++h)
        acc += sE[fr * 513 + h] * sW[h * 16 + c];
    out[(size_t)(f0 + fr) * 16 + c] = acc;
}

// ---------------------------------------------------------------------------
// Workspace layout (~156.4 MB):
//   W1F 1 MB | W2F 4 MB | NF 134 MB | EMB 16 MB | MEAN 64K | RSIG 64K
// ---------------------------------------------------------------------------
extern "C" void kernel_launch(void* const* d_in, const int* in_sizes, int n_in,
                              void* d_out, int out_size, void* d_ws, size_t ws_size,
                              hipStream_t stream)
{
    const float* x     = (const float*)d_in[0];
    const int*   gidx  = (const int*)d_in[1];
    const float* W1    = (const float*)d_in[4];
    const float* b1    = (const float*)d_in[5];
    const float* W2    = (const float*)d_in[6];
    const float* b2    = (const float*)d_in[7];
    const float* w_out = (const float*)d_in[8];
    const float* b_out = (const float*)d_in[9];
    float* out = (float*)d_out;

    char* w = (char*)d_ws;
    bf16* W1F = (bf16*)w;  w += (size_t)NGRP * KEXP * D_IN * 2;
    bf16* W2F = (bf16*)w;  w += (size_t)NGRP * H_DIM * KEXP * 2;
    bf16* NF  = (bf16*)w;  w += (size_t)N_NODES * H_DIM * 2;
    float* EMB  = (float*)w; w += (size_t)F_SEG * H_DIM * 4;
    float* MEAN = (float*)w; w += (size_t)G_SEG * H_DIM * 4;
    float* RSIG = (float*)w; w += (size_t)G_SEG * H_DIM * 4;

    convert_weights<<<1280, 256, 0, stream>>>(W1, W2, W1F, W2F);
    mlp_kernel<<<4096, 256, 0, stream>>>(x, gidx, W1F, b1, W2F, b2, NF);
    pool_kernel<<<8192, 256, 0, stream>>>(NF, EMB);
    stats_kernel<<<dim3(32, 4), 128, 0, stream>>>(EMB, MEAN, RSIG);
    classifier_kernel<<<512, 256, 0, stream>>>(EMB, MEAN, RSIG, w_out, b_out, out);
}